// Round 11
// baseline (6702.393 us; speedup 1.0000x reference)
//
#include <hip/hip_runtime.h>
#include <cmath>

#define NG 128
#define SMEM_BYTES 10240
#define GRID_BLOCKS 1024   // 4 blocks/CU x 256 CUs; co-residency by __launch_bounds__(256,4)

typedef _Float16 half8 __attribute__((ext_vector_type(8)));
typedef _Float16 half4v __attribute__((ext_vector_type(4)));
typedef _Float16 half2v __attribute__((ext_vector_type(2)));
typedef float f32x4 __attribute__((ext_vector_type(4)));

#if defined(__has_builtin)
# if __has_builtin(__builtin_amdgcn_fdot2)
#  define USE_FDOT2 1
# endif
# if __has_builtin(__builtin_amdgcn_update_dpp)
#  define USE_DPP 1
# endif
# if __has_builtin(__builtin_amdgcn_exp2f)
#  define EX2(x) __builtin_amdgcn_exp2f(x)
# endif
# if __has_builtin(__builtin_amdgcn_s_sleep)
#  define SSLEEP() __builtin_amdgcn_s_sleep(2)
# endif
#endif
#ifndef EX2
# define EX2(x) exp2f(x)
#endif
#ifndef SSLEEP
# define SSLEEP()
#endif

__device__ inline float dpp_sum8(float p) {
#ifdef USE_DPP
    int pi = __builtin_bit_cast(int, p);
    int a = __builtin_amdgcn_update_dpp(0, pi, 0xB1, 0xF, 0xF, true);
    p += __builtin_bit_cast(float, a);
    pi = __builtin_bit_cast(int, p);
    a = __builtin_amdgcn_update_dpp(0, pi, 0x4E, 0xF, 0xF, true);
    p += __builtin_bit_cast(float, a);
    pi = __builtin_bit_cast(int, p);
    a = __builtin_amdgcn_update_dpp(0, pi, 0x141, 0xF, 0xF, true);
    p += __builtin_bit_cast(float, a);
    return p;
#else
    p += __shfl_xor(p, 1); p += __shfl_xor(p, 2); p += __shfl_xor(p, 4);
    return p;
#endif
}

// device-scope grid barrier (generation + sense; agent-scope atomics handle XCD L2s).
// Bounded spin: converts a co-residency failure into a wrong answer, never a hang.
__device__ inline void gsync(unsigned* cnt, unsigned* gen) {
    __syncthreads();
    __threadfence();
    if (threadIdx.x == 0) {
        unsigned g = __hip_atomic_load(gen, __ATOMIC_RELAXED, __HIP_MEMORY_SCOPE_AGENT);
        unsigned arrived = __hip_atomic_fetch_add(cnt, 1u, __ATOMIC_ACQ_REL, __HIP_MEMORY_SCOPE_AGENT);
        if (arrived == gridDim.x - 1) {
            __hip_atomic_store(cnt, 0u, __ATOMIC_RELAXED, __HIP_MEMORY_SCOPE_AGENT);
            __hip_atomic_fetch_add(gen, 1u, __ATOMIC_ACQ_REL, __HIP_MEMORY_SCOPE_AGENT);
        } else {
            long spin = 0;
            while (__hip_atomic_load(gen, __ATOMIC_ACQUIRE, __HIP_MEMORY_SCOPE_AGENT) == g) {
                SSLEEP();
                if (++spin > (1L << 24)) break;   // safety valve
            }
        }
    }
    __syncthreads();
    __threadfence();
}

struct MegaArgs {
    const float *feat, *Wsrc, *bsrc, *Wdst, *bdst, *attn, *bn_g, *bn_b;
    const float *lpW, *lpb, *lpg, *lpbt, *blW, *blb, *blg, *blbt;
    const float *llW, *llb, *llg, *llbt;
    const int *src, *dst, *gid;
    float* out;
    _Float16 *fsh, *fdh;
    float *hmean, *q;
    float *hh;
    _Float16 *Wt, *att16;
    float *bnsum, *bnsq, *qsum, *qsq, *hsum, *hsq, *S;
    int *deg, *gbase, *cntg, *gstart, *row_ptr, *col_src, *pos;
    unsigned *bar;                      // [cnt, gen]
    int N, E, hbItems, nb, scatItems, gemmTiles, gatItems;
    float invN;
};

// ---------------- phases (gridDim-strided; per-block trip counts uniform) ----------------

__device__ void phase_wcvt_hb(const MegaArgs& a, char* smem) {
    int t = threadIdx.x, G = gridDim.x;
    for (int it = blockIdx.x; it < 24 + a.hbItems; it += G) {
        if (it < 24) {
            _Float16* lt = (_Float16*)smem;     // 64*68*2 = 8704 B
            int mat = it >> 2, ct = it & 3, c0 = ct * 64;
            const float* W = ((mat & 1) ? a.Wdst : a.Wsrc) + (size_t)(mat >> 1) * 16384;
            _Float16* o = a.Wt + (size_t)mat * 16384;
#pragma unroll
            for (int i = 0; i < 16; i++) {
                int flat = i * 256 + t;
                int k = flat >> 6, c = flat & 63;
                lt[c * 68 + k] = (_Float16)W[k * 256 + c0 + c];
            }
            __syncthreads();
#pragma unroll
            for (int i = 0; i < 16; i++) {
                int flat = i * 256 + t;
                int c = flat >> 6, k = flat & 63;
                o[(size_t)(c0 + c) * 64 + k] = lt[c * 68 + k];
            }
            if (it == 0)
                for (int i = t; i < 768; i += 256)
                    a.att16[i] = (_Float16)(a.attn[i] * 1.44269504f);   // fold log2(e)
            __syncthreads();
        } else {
            int i = (it - 24) * 256 + t;
            if (i < a.E) a.pos[i] = atomicAdd(&a.deg[a.dst[i]], 1);
            if (i < a.N) {
                int aa = a.gid[i];
                if (i == 0)
                    for (int g = 0; g <= aa; g++) a.gstart[g] = 0;
                int b2 = (i + 1 < a.N) ? a.gid[i + 1] : NG;
                for (int g = aa + 1; g <= b2 && g < NG; g++) a.gstart[g] = i + 1;
            }
        }
    }
}

__device__ void phase_rowptr(const MegaArgs& a, char* smem) {
    int t = threadIdx.x, G = gridDim.x;
    int* red = (int*)smem;
    __shared__ int base_s;
    for (int b = blockIdx.x; b < a.nb; b += G) {
        int base = b * 1024 + t * 4;
        int dp[4];
        int s = 0;
#pragma unroll
        for (int j = 0; j < 4; j++) {
            int i = base + j;
            int d = (i < a.N) ? a.deg[i] : 0;
            dp[j] = (d + 3) & ~3;              // pad rows to 4 -> 16B-aligned int4 loads
            s += dp[j];
        }
        red[t] = s;
        __syncthreads();
        for (int off = 1; off < 256; off <<= 1) {
            int v = (t >= off) ? red[t - off] : 0;
            __syncthreads();
            red[t] += v;
            __syncthreads();
        }
        if (t == 255) base_s = atomicAdd(a.gbase, red[255]);
        __syncthreads();
        int excl = red[t] - s + base_s;
#pragma unroll
        for (int j = 0; j < 4; j++) {
            int i = base + j;
            if (i < a.N) a.row_ptr[i] = excl;
            excl += dp[j];
        }
        __syncthreads();
    }
    if (blockIdx.x == G - 1 && t < NG) {
        int s1 = (t == NG - 1) ? a.N : a.gstart[t + 1];
        a.cntg[t] = s1 - a.gstart[t];
    }
}

__device__ void gemm_tile(const MegaArgs& a, char* smem, int tile, int l) {
    _Float16* As = (_Float16*)smem;            // 64*72*2 = 9216 B
    int t = threadIdx.x;
    int row0 = tile * 64;
    const float* h = (l == 0) ? a.feat : a.hmean;
    const float* bs_ = a.bnsum + (l - 1) * 64;
    const float* bq_ = a.bnsq + (l - 1) * 64;
    const float* g_  = a.bn_g + (l - 1) * 64;
    const float* b_  = a.bn_b + (l - 1) * 64;
#pragma unroll
    for (int i = 0; i < 4; i++) {
        int flat = i * 256 + t;
        int r = flat >> 4, kg = flat & 15;
        int gr = row0 + r;
        float4 hv = make_float4(0.f, 0.f, 0.f, 0.f);
        if (gr < a.N) hv = *(const float4*)(h + (size_t)gr * 64 + kg * 4);
        float4 a4, b4;
        if (l == 0) {
            a4 = make_float4(1.f, 1.f, 1.f, 1.f);
            b4 = make_float4(0.f, 0.f, 0.f, 0.f);
        } else {
            float4 s4 = *(const float4*)(bs_ + kg * 4);
            float4 q4 = *(const float4*)(bq_ + kg * 4);
            float4 g4 = *(const float4*)(g_ + kg * 4);
            float4 t4 = *(const float4*)(b_ + kg * 4);
            float mu;
            mu = s4.x * a.invN; a4.x = g4.x * rsqrtf(q4.x * a.invN - mu * mu + 1e-5f); b4.x = t4.x - mu * a4.x;
            mu = s4.y * a.invN; a4.y = g4.y * rsqrtf(q4.y * a.invN - mu * mu + 1e-5f); b4.y = t4.y - mu * a4.y;
            mu = s4.z * a.invN; a4.z = g4.z * rsqrtf(q4.z * a.invN - mu * mu + 1e-5f); b4.z = t4.z - mu * a4.z;
            mu = s4.w * a.invN; a4.w = g4.w * rsqrtf(q4.w * a.invN - mu * mu + 1e-5f); b4.w = t4.w - mu * a4.w;
        }
        half4v o4;
        o4[0] = (_Float16)(hv.x * a4.x + b4.x);
        o4[1] = (_Float16)(hv.y * a4.y + b4.y);
        o4[2] = (_Float16)(hv.z * a4.z + b4.z);
        o4[3] = (_Float16)(hv.w * a4.w + b4.w);
        *(half4v*)(&As[r * 72 + kg * 4]) = o4;
    }
    __syncthreads();

    int w = t >> 6, lane = t & 63;
    int n16 = lane & 15, qd = lane >> 4;
    int cw = w * 64;
    const _Float16* Wt_l = a.Wt + (size_t)l * 32768;
#pragma unroll
    for (int y = 0; y < 2; y++) {
        const _Float16* Wm = Wt_l + (size_t)y * 16384;
        const float* bias = (y ? a.bdst : a.bsrc) + l * 256;
        _Float16* outp = y ? a.fdh : a.fsh;
        f32x4 acc[4][4];
#pragma unroll
        for (int mt = 0; mt < 4; mt++)
#pragma unroll
            for (int nt = 0; nt < 4; nt++) acc[mt][nt] = (f32x4)(0.f);
        float bv[4];
#pragma unroll
        for (int nt = 0; nt < 4; nt++) bv[nt] = bias[cw + nt * 16 + n16];
#pragma unroll
        for (int kk = 0; kk < 2; kk++) {
            half8 af[4], bf[4];
#pragma unroll
            for (int mt = 0; mt < 4; mt++)
                af[mt] = *(const half8*)(&As[(mt * 16 + n16) * 72 + kk * 32 + qd * 8]);
#pragma unroll
            for (int nt = 0; nt < 4; nt++)
                bf[nt] = *(const half8*)(Wm + (size_t)(cw + nt * 16 + n16) * 64 + kk * 32 + qd * 8);
#pragma unroll
            for (int mt = 0; mt < 4; mt++)
#pragma unroll
                for (int nt = 0; nt < 4; nt++)
                    acc[mt][nt] = __builtin_amdgcn_mfma_f32_16x16x32_f16(af[mt], bf[nt], acc[mt][nt], 0, 0, 0);
        }
#pragma unroll
        for (int mt = 0; mt < 4; mt++) {
#pragma unroll
            for (int i = 0; i < 4; i++) {
                int gr = row0 + mt * 16 + qd * 4 + i;
                if (gr < a.N) {
#pragma unroll
                    for (int nt = 0; nt < 4; nt++)
                        outp[(size_t)gr * 256 + cw + nt * 16 + n16] = (_Float16)(acc[mt][nt][i] + bv[nt]);
                }
            }
        }
    }
    __syncthreads();
}

__device__ void pooled_block(const MegaArgs& a, char* smem, int g, int lp) {
    float* sv = (float*)smem;                        // 64
    float (*partial)[64] = (float(*)[64])(smem + 256);
    int t = threadIdx.x;
    const float* bs_ = a.bnsum + lp * 64;
    const float* bq_ = a.bnsq + lp * 64;
    const float* lpW_l = a.lpW + (size_t)lp * 4096;
    if (t < 64) {
        float mu = bs_[t] * a.invN;
        float var = bq_[t] * a.invN - mu * mu;
        float aa = a.bn_g[lp * 64 + t] * rsqrtf(var + 1e-5f);
        float bb = a.bn_b[lp * 64 + t] - mu * aa;
        sv[t] = aa * a.S[lp * 8192 + g * 64 + t] + bb * (float)a.cntg[g];
    }
    __syncthreads();
    int f = t & 63, kc = t >> 6;
    float acc = 0.f;
#pragma unroll
    for (int k = kc * 16; k < kc * 16 + 16; k++)
        acc = fmaf(sv[k], lpW_l[k * 64 + f], acc);
    partial[kc][f] = acc;
    __syncthreads();
    if (t < 64) {
        float v = partial[0][t] + partial[1][t] + partial[2][t] + partial[3][t] + a.lpb[lp * 64 + t];
        v = fmaxf(v, 0.f);
        a.q[lp * 8192 + g * 64 + t] = v;
        atomicAdd(&a.qsum[lp * 64 + t], v);
        atomicAdd(&a.qsq[lp * 64 + t], v * v);
    }
    __syncthreads();
}

__device__ void phase_gemm(const MegaArgs& a, char* smem, int l) {
    int t = threadIdx.x, G = gridDim.x;
    int extra = (l == 0) ? a.scatItems : NG;
    for (int it = blockIdx.x; it < a.gemmTiles + extra; it += G) {
        if (it < extra) {
            if (l == 0) {
                int e = it * 256 + t;
                if (e < a.E) {
                    int d = a.dst[e];
                    a.col_src[a.row_ptr[d] + a.pos[e]] = a.src[e] << 8;  // f16-elem row offset
                }
            } else {
                pooled_block(a, smem, it, l - 1);
            }
        } else {
            gemm_tile(a, smem, it - extra, l);
        }
    }
}

__device__ void gat_node(const MegaArgs& a, int wid, const _Float16* att_l) {
    int lane = threadIdx.x & 63;
    int e2 = lane >> 5;
    int d8 = lane & 31;
    int rs = a.row_ptr[wid];
    int deg = a.deg[wid];
    const int* cs = a.col_src + rs;
    const _Float16* fsb = a.fsh + d8 * 8;

    half8 fdv = *(const half8*)(a.fdh + (size_t)wid * 256 + d8 * 8);
    half8 att = *(const half8*)(att_l + (d8 >> 3) * 64 + (d8 & 7) * 8);
    half8 k02;
#pragma unroll
    for (int j = 0; j < 8; j++) k02[j] = (_Float16)0.2f;

    float acc[8];
#pragma unroll
    for (int j = 0; j < 8; j++) acc[j] = 0.f;
    float l = 0.f;

    auto body = [&](half8 fv) {
        half8 x = fv + fdv;
        half8 lx = __builtin_elementwise_max(x, x * k02);
        float p = 0.f;
#ifdef USE_FDOT2
#pragma unroll
        for (int j = 0; j < 4; j++) {
            half2v a2 = { lx[2 * j], lx[2 * j + 1] };
            half2v b2 = { att[2 * j], att[2 * j + 1] };
            p = __builtin_amdgcn_fdot2(a2, b2, p, false);
        }
#else
#pragma unroll
        for (int j = 0; j < 8; j++) p = fmaf((float)lx[j], (float)att[j], p);
#endif
        p = dpp_sum8(p);
        float e = EX2(p);
        l += e;
#pragma unroll
        for (int j = 0; j < 8; j++) acc[j] = fmaf(e, (float)fv[j], acc[j]);
    };

    int deg8 = deg & ~7;
    int4 nsv;
    if (deg8 > 0) nsv = *(const int4*)(cs + 4 * e2);
    for (int i = 0; i < deg8; i += 8) {
        int4 sv = nsv;
        if (i + 8 < deg8) nsv = *(const int4*)(cs + i + 8 + 4 * e2);
        half8 f0 = *(const half8*)(fsb + (size_t)(unsigned)sv.x);
        half8 f1 = *(const half8*)(fsb + (size_t)(unsigned)sv.y);
        body(f0);
        half8 f2 = *(const half8*)(fsb + (size_t)(unsigned)sv.z);
        body(f1);
        half8 f3 = *(const half8*)(fsb + (size_t)(unsigned)sv.w);
        body(f2);
        body(f3);
    }
    for (int idx = deg8 + e2; idx < deg; idx += 2) {
        int s = cs[idx];
        half8 fv = *(const half8*)(fsb + (size_t)(unsigned)s);
        body(fv);
    }

    l += __shfl_xor(l, 32);
#pragma unroll
    for (int j = 0; j < 8; j++) acc[j] += __shfl_xor(acc[j], 32);

    float inv = (l > 0.f) ? 0.25f / l : 0.f;   // head-mean folded
    float m[8];
#pragma unroll
    for (int j = 0; j < 8; j++) m[j] = fmaxf(acc[j] * inv, 0.f);
#pragma unroll
    for (int j = 0; j < 8; j++) {
        m[j] += __shfl_xor(m[j], 8);
        m[j] += __shfl_xor(m[j], 16);
    }
    if (lane < 8) {
        float4 o0 = make_float4(m[0], m[1], m[2], m[3]);
        float4 o1 = make_float4(m[4], m[5], m[6], m[7]);
        *(float4*)(a.hmean + (size_t)wid * 64 + d8 * 8) = o0;
        *(float4*)(a.hmean + (size_t)wid * 64 + d8 * 8 + 4) = o1;
    }
}

__device__ void phase_gat(const MegaArgs& a, int l) {
    int G = gridDim.x;
    const _Float16* att_l = a.att16 + l * 256;
    for (int it = blockIdx.x; it < a.gatItems; it += G) {
        int wid = it * 4 + (threadIdx.x >> 6);
        if (wid < a.N) gat_node(a, wid, att_l);
    }
}

__device__ void stats_block(const MegaArgs& a, char* smem, int sb, int l) {
    float (*bs)[64] = (float(*)[64])smem;
    float (*bq)[64] = (float(*)[64])(smem + 1024);
    float* bnsum_l = a.bnsum + l * 64;
    float* bnsq_l  = a.bnsq + l * 64;
    float* S_l     = a.S + l * 8192;
    int t = threadIdx.x, lane = t & 63, w = t >> 6;
    int wglobal = sb * 4 + w;
    int chunk = (a.N + 511) >> 9;
    int n0 = wglobal * chunk;
    int n1 = min(n0 + chunk, a.N);
    float sum = 0.f, sq = 0.f, run = 0.f;
    int cur = -1;
    for (int n = n0; n < n1; n++) {
        float v = a.hmean[(size_t)n * 64 + lane];
        int g = a.gid[n];
        if (g != cur) {
            if (cur >= 0) atomicAdd(&S_l[cur * 64 + lane], run);
            run = 0.f;
            cur = g;
        }
        run += v;
        sum += v;
        sq = fmaf(v, v, sq);
    }
    if (cur >= 0) atomicAdd(&S_l[cur * 64 + lane], run);
    bs[w][lane] = sum;
    bq[w][lane] = sq;
    __syncthreads();
    if (w == 0) {
        float s2 = bs[0][lane] + bs[1][lane] + bs[2][lane] + bs[3][lane];
        float q2 = bq[0][lane] + bq[1][lane] + bq[2][lane] + bq[3][lane];
        atomicAdd(&bnsum_l[lane], s2);
        atomicAdd(&bnsq_l[lane], q2);
    }
    __syncthreads();
}

__device__ void phase_stats(const MegaArgs& a, char* smem, int l) {
    int G = gridDim.x;
    for (int it = blockIdx.x; it < 128; it += G)
        stats_block(a, smem, it, l);
}

__device__ void headgemm_block(const MegaArgs& a, char* smem, int g) {
    float* cat = (float*)smem;                       // 192
    float (*partial)[64] = (float(*)[64])(smem + 768);
    int t = threadIdx.x;
    if (t < 192) {
        int ci = t >> 6, f = t & 63;
        float mu = a.qsum[ci * 64 + f] * (1.f / 128.f);
        float var = a.qsq[ci * 64 + f] * (1.f / 128.f) - mu * mu;
        float sc = a.lpg[ci * 64 + f] * rsqrtf(var + 1e-5f);
        cat[t] = (a.q[ci * 8192 + g * 64 + f] - mu) * sc + a.lpbt[ci * 64 + f];
    }
    __syncthreads();
    int f = t & 63, kc = t >> 6;
    float acc = 0.f;
#pragma unroll
    for (int k = kc * 48; k < kc * 48 + 48; k++)
        acc = fmaf(cat[k], a.blW[k * 64 + f], acc);
    partial[kc][f] = acc;
    __syncthreads();
    if (t < 64) {
        float v = partial[0][t] + partial[1][t] + partial[2][t] + partial[3][t] + a.blb[t];
        v = fmaxf(v, 0.f);
        a.hh[g * 64 + t] = v;
        atomicAdd(&a.hsum[t], v);
        atomicAdd(&a.hsq[t], v * v);
    }
    __syncthreads();
}

__device__ void phase_headgemm(const MegaArgs& a, char* smem) {
    int G = gridDim.x;
    for (int it = blockIdx.x; it < NG; it += G)
        headgemm_block(a, smem, it);
}

__device__ void phase_pooled2(const MegaArgs& a, char* smem) {
    int G = gridDim.x;
    for (int it = blockIdx.x; it < NG; it += G)
        pooled_block(a, smem, it, 2);
}

__device__ void headfinish_block(const MegaArgs& a, char* smem) {
    float* mu = (float*)smem;            // 64
    float* sc = mu + 64;                 // 64
    float* mj = sc + 64;                 // 16
    float* scj = mj + 16;                // 16
    float* sW = scj + 16;                // 640
    float (*ph)[12] = (float(*)[12])(sW + 640);   // 128*12 -> total 9344 B
    int t = threadIdx.x;
    if (t < 64) {
        float m = a.hsum[t] * (1.f / 128.f);
        float v = a.hsq[t] * (1.f / 128.f) - m * m;
        mu[t] = m;
        sc[t] = a.blg[t] / sqrtf(v + 1e-5f);
    }
    for (int i = t; i < 640; i += 256) sW[i] = a.llW[i];
    __syncthreads();
    for (int i = t; i < 8192; i += 256) {
        int ff = i & 63;
        float v = (a.hh[i] - mu[ff]) * sc[ff] + a.blbt[ff];
        a.out[1280 + i] = v;          // output 1: pooled_hh
    }
    __syncthreads();
    for (int i = t; i < 1280; i += 256) {
        int g = i / 10, j = i - g * 10;
        float s = a.llb[j];
#pragma unroll 8
        for (int k = 0; k < 64; k++)
            s = fmaf(a.out[1280 + g * 64 + k], sW[k * 10 + j], s);   // fresh lines, same CU
        ph[g][j] = fmaxf(s, 0.f);
    }
    __syncthreads();
    if (t < 10) {
        float m = 0.f;
        for (int g = 0; g < 128; g++) m += ph[g][t];
        m *= (1.f / 128.f);
        float v = 0.f;
        for (int g = 0; g < 128; g++) { float d = ph[g][t] - m; v = fmaf(d, d, v); }
        v *= (1.f / 128.f);
        mj[t] = m;
        scj[t] = a.llg[t] / sqrtf(v + 1e-5f);
    }
    __syncthreads();
    if (t < 128) {
        float vals[10];
        float mx = -1e30f;
        for (int j = 0; j < 10; j++) {
            vals[j] = (ph[t][j] - mj[j]) * scj[j] + a.llbt[j];
            mx = fmaxf(mx, vals[j]);
        }
        float se = 0.f;
        for (int j = 0; j < 10; j++) se += __expf(vals[j] - mx);
        float lse = logf(se) + mx;
        for (int j = 0; j < 10; j++) a.out[t * 10 + j] = vals[j] - lse;   // output 0
    }
}

// ---------------- persistent mega-kernel (plain launch; capture-safe) ----------------

__global__ void __launch_bounds__(256, 4) mega_kernel(MegaArgs a) {
    __shared__ __align__(16) char smem[SMEM_BYTES];
    unsigned* cnt = a.bar;
    unsigned* gen = a.bar + 1;

    phase_wcvt_hb(a, smem);
    gsync(cnt, gen);
    phase_rowptr(a, smem);
    gsync(cnt, gen);
    for (int l = 0; l < 3; l++) {
        phase_gemm(a, smem, l);      // + scatter (l=0) / pooled(l-1) (l>=1)
        gsync(cnt, gen);
        phase_gat(a, l);
        gsync(cnt, gen);
        phase_stats(a, smem, l);
        gsync(cnt, gen);
    }
    phase_pooled2(a, smem);
    gsync(cnt, gen);
    phase_headgemm(a, smem);
    gsync(cnt, gen);
    if (blockIdx.x == 0) headfinish_block(a, smem);
}

// ---------------- launcher ----------------

extern "C" void kernel_launch(void* const* d_in, const int* in_sizes, int n_in,
                              void* d_out, int out_size, void* d_ws, size_t ws_size,
                              hipStream_t stream)
{
    MegaArgs a;
    a.feat = (const float*)d_in[0];
    a.Wsrc = (const float*)d_in[1];
    a.bsrc = (const float*)d_in[2];
    a.Wdst = (const float*)d_in[3];
    a.bdst = (const float*)d_in[4];
    a.attn = (const float*)d_in[5];
    a.bn_g = (const float*)d_in[6];
    a.bn_b = (const float*)d_in[7];
    a.lpW  = (const float*)d_in[8];
    a.lpb  = (const float*)d_in[9];
    a.lpg  = (const float*)d_in[10];
    a.lpbt = (const float*)d_in[11];
    a.blW  = (const float*)d_in[12];
    a.blb  = (const float*)d_in[13];
    a.blg  = (const float*)d_in[14];
    a.blbt = (const float*)d_in[15];
    a.llW  = (const float*)d_in[16];
    a.llb  = (const float*)d_in[17];
    a.llg  = (const float*)d_in[18];
    a.llbt = (const float*)d_in[19];
    a.src  = (const int*)d_in[20];
    a.dst  = (const int*)d_in[21];
    a.gid  = (const int*)d_in[22];
    a.out  = (float*)d_out;

    int N = in_sizes[0] / 64;
    int E = in_sizes[20];
    a.N = N; a.E = E;
    a.invN = 1.f / (float)N;
    a.hbItems = ((E > N ? E : N) + 255) / 256;
    a.nb = (N + 1023) / 1024;
    a.scatItems = (E + 255) / 256;
    a.gemmTiles = (N + 63) / 64;
    a.gatItems = (N + 3) / 4;

    // workspace layout (same as R9)
    float* wsf = (float*)d_ws;
    a.fsh = (_Float16*)wsf;                           // N*256 f16
    a.fdh = (_Float16*)(wsf + (size_t)N * 128);       // N*256 f16
    a.hmean = wsf + (size_t)N * 256;                  // N*64
    a.q     = a.hmean + (size_t)N * 64;               // 3*8192
    a.hh    = a.q + 24576;                            // 8192
    a.Wt    = (_Float16*)(a.hh + 8192);               // 6*16384 f16
    a.att16 = (_Float16*)(a.hh + 8192 + 49152);       // 768 f16
    float* zstart = a.hh + 8192 + 49152 + 384;
    a.bnsum = zstart;                                 // 3*64
    a.bnsq  = a.bnsum + 192;
    a.qsum  = a.bnsq + 192;
    a.qsq   = a.qsum + 192;
    a.hsum  = a.qsq + 192;                            // 64
    a.hsq   = a.hsum + 64;                            // 64
    a.S     = a.hsq + 64;                             // 3*8192
    a.deg   = (int*)(a.S + 24576);                    // N
    a.gbase = a.deg + N;                              // 4
    a.bar   = (unsigned*)(a.gbase + 4);               // 4 (cnt, gen, pad)
    int* zend = (int*)(a.bar + 4);
    a.cntg    = zend;                                 // 128
    a.gstart  = a.cntg + 128;                         // 128
    a.row_ptr = a.gstart + 128;                       // N
    a.col_src = a.row_ptr + N;                        // E + 3N + 64 (padded rows)
    a.pos     = a.col_src + E + 3 * N + 64;           // E

    size_t zbytes = (size_t)((char*)zend - (char*)zstart);
    hipMemsetAsync(zstart, 0, zbytes, stream);

    hipLaunchKernelGGL(mega_kernel, dim3(GRID_BLOCKS), dim3(256), 0, stream, a);
}

// Round 12
// 607.430 us; speedup vs baseline: 11.0340x; 11.0340x over previous
//
#include <hip/hip_runtime.h>
#include <cmath>

#define NH 4
#define NG 128

typedef _Float16 half8 __attribute__((ext_vector_type(8)));
typedef _Float16 half4v __attribute__((ext_vector_type(4)));
typedef _Float16 half2v __attribute__((ext_vector_type(2)));
typedef float f32x4 __attribute__((ext_vector_type(4)));

#if defined(__has_builtin)
# if __has_builtin(__builtin_amdgcn_fdot2)
#  define USE_FDOT2 1
# endif
# if __has_builtin(__builtin_amdgcn_update_dpp)
#  define USE_DPP 1
# endif
# if __has_builtin(__builtin_amdgcn_exp2f)
#  define EX2(x) __builtin_amdgcn_exp2f(x)
# endif
#endif
#ifndef EX2
# define EX2(x) exp2f(x)
#endif

__device__ inline float vload(const float* p) { return *(volatile const float*)p; }

__device__ inline float dpp_sum8(float p) {
#ifdef USE_DPP
    int pi = __builtin_bit_cast(int, p);
    int a = __builtin_amdgcn_update_dpp(0, pi, 0xB1, 0xF, 0xF, true);
    p += __builtin_bit_cast(float, a);
    pi = __builtin_bit_cast(int, p);
    a = __builtin_amdgcn_update_dpp(0, pi, 0x4E, 0xF, 0xF, true);
    p += __builtin_bit_cast(float, a);
    pi = __builtin_bit_cast(int, p);
    a = __builtin_amdgcn_update_dpp(0, pi, 0x141, 0xF, 0xF, true);
    p += __builtin_bit_cast(float, a);
    return p;
#else
    p += __shfl_xor(p, 1); p += __shfl_xor(p, 2); p += __shfl_xor(p, 4);
    return p;
#endif
}

// ------- fused: W->Wt[c][k] f16 (24 tile-blocks) + hist/pos + graph bounds -------

__global__ void __launch_bounds__(256) wcvt_hb_kernel(
    const float* __restrict__ Wsrc, const float* __restrict__ Wdst,
    const float* __restrict__ attn,
    _Float16* __restrict__ Wt, _Float16* __restrict__ att16,
    const int* __restrict__ dst, int* __restrict__ deg, int* __restrict__ pos,
    const int* __restrict__ gid, int* __restrict__ gstart, int N, int E)
{
    int t = threadIdx.x;
    if (blockIdx.x < 24) {
        __shared__ _Float16 lt[64 * 68];
        int b = blockIdx.x;
        int mat = b >> 2, ct = b & 3;
        int c0 = ct * 64;
        const float* W = ((mat & 1) ? Wdst : Wsrc) + (size_t)(mat >> 1) * 16384;
        _Float16* o = Wt + (size_t)mat * 16384;
#pragma unroll
        for (int i = 0; i < 16; i++) {
            int flat = i * 256 + t;
            int k = flat >> 6, c = flat & 63;
            lt[c * 68 + k] = (_Float16)W[k * 256 + c0 + c];
        }
        __syncthreads();
#pragma unroll
        for (int i = 0; i < 16; i++) {
            int flat = i * 256 + t;
            int c = flat >> 6, k = flat & 63;
            o[(size_t)(c0 + c) * 64 + k] = lt[c * 68 + k];
        }
        if (b == 0)
            for (int i = t; i < 3 * 256; i += 256)
                att16[i] = (_Float16)(attn[i] * 1.44269504f);   // fold log2(e)
        return;
    }
    int i = (blockIdx.x - 24) * 256 + t;
    if (i < E) pos[i] = atomicAdd(&deg[dst[i]], 1);
    if (i < N) {
        int a = gid[i];
        if (i == 0)
            for (int g = 0; g <= a; g++) gstart[g] = 0;
        int b2 = (i + 1 < N) ? gid[i + 1] : NG;
        for (int g = a + 1; g <= b2 && g < NG; g++) gstart[g] = i + 1;
    }
}

// single-dispatch row offsets, rows padded to multiples of 4 (for int4 col_src loads)
__global__ void __launch_bounds__(256) rowptr_kernel(const int* __restrict__ deg,
                                                     int* __restrict__ row_ptr,
                                                     int* __restrict__ gbase,
                                                     const int* __restrict__ gstart,
                                                     int* __restrict__ cntg, int N) {
    __shared__ int red[256];
    __shared__ int base_s;
    int t = threadIdx.x;
    int base = blockIdx.x * 1024 + t * 4;
    int dp[4];
    int s = 0;
#pragma unroll
    for (int j = 0; j < 4; j++) {
        int i = base + j;
        int d = (i < N) ? deg[i] : 0;
        dp[j] = (d + 3) & ~3;
        s += dp[j];
    }
    red[t] = s;
    __syncthreads();
    for (int off = 1; off < 256; off <<= 1) {
        int v = (t >= off) ? red[t - off] : 0;
        __syncthreads();
        red[t] += v;
        __syncthreads();
    }
    if (t == 255) base_s = atomicAdd(gbase, red[255]);
    __syncthreads();
    int excl = red[t] - s + base_s;
#pragma unroll
    for (int j = 0; j < 4; j++) {
        int i = base + j;
        if (i < N) row_ptr[i] = excl;
        excl += dp[j];
    }
    if (blockIdx.x == 0 && t < NG) {
        int s1 = (t == NG - 1) ? N : gstart[t + 1];
        cntg[t] = s1 - gstart[t];
    }
}

// ------- fused BN-affine + dual GEMM (f16 MFMA); extra roles: scatter, pooled MLP -------

__global__ void __launch_bounds__(512) gemm_kernel(
    const float* __restrict__ h,
    const float* __restrict__ bnsum, const float* __restrict__ bnsq,
    const float* __restrict__ bn_g, const float* __restrict__ bn_b,
    int isl0, float invN,
    const _Float16* __restrict__ Wt,
    const float* __restrict__ bsrc, const float* __restrict__ bdst,
    _Float16* __restrict__ fsh, _Float16* __restrict__ fdh, int N,
    int gemmBlocks, int scatBlocks,
    const int* __restrict__ src, const int* __restrict__ dst,
    const int* __restrict__ row_ptr, const int* __restrict__ pos,
    int* __restrict__ col_src, int E,
    const float* __restrict__ S, const int* __restrict__ cntg,
    const float* __restrict__ plpW, const float* __restrict__ plpb,
    float* __restrict__ q, float* __restrict__ qsum, float* __restrict__ qsq)
{
    int t = threadIdx.x;
    if (blockIdx.x >= gemmBlocks) {
        int pb = blockIdx.x - gemmBlocks - scatBlocks;
        if (pb < 0) {                         // scatter role (atomic-free)
            int e = (blockIdx.x - gemmBlocks) * 512 + t;
            if (e < E) {
                int d = dst[e];
                col_src[row_ptr[d] + pos[e]] = src[e] << 8;   // f16-element row offset
            }
            return;
        }
        // pooled role: graph pb, layer l-1
        __shared__ float sv[64];
        __shared__ float partial[8][64];
        if (t < 64) {
            float mu = bnsum[t] * invN;
            float var = bnsq[t] * invN - mu * mu;
            float aa = bn_g[t] * rsqrtf(var + 1e-5f);
            float bb = bn_b[t] - mu * aa;
            sv[t] = aa * S[pb * 64 + t] + bb * (float)cntg[pb];
        }
        __syncthreads();
        int f = t & 63, kc = t >> 6;
        float acc = 0.f;
#pragma unroll
        for (int k = kc * 8; k < kc * 8 + 8; k++)
            acc = fmaf(sv[k], plpW[k * 64 + f], acc);
        partial[kc][f] = acc;
        __syncthreads();
        if (t < 64) {
            float v = plpb[t];
#pragma unroll
            for (int j = 0; j < 8; j++) v += partial[j][t];
            v = fmaxf(v, 0.f);
            q[pb * 64 + t] = v;
            atomicAdd(&qsum[t], v);
            atomicAdd(&qsq[t], v * v);
        }
        return;
    }
    __shared__ _Float16 As[64 * 72];
    int row0 = blockIdx.x * 64;

#pragma unroll
    for (int i = 0; i < 2; i++) {
        int flat = i * 512 + t;
        int r = flat >> 4, kg = flat & 15;
        int gr = row0 + r;
        float4 hv = make_float4(0.f, 0.f, 0.f, 0.f);
        if (gr < N) hv = *(const float4*)(h + (size_t)gr * 64 + kg * 4);
        float4 a4, b4;
        if (isl0) {
            a4 = make_float4(1.f, 1.f, 1.f, 1.f);
            b4 = make_float4(0.f, 0.f, 0.f, 0.f);
        } else {
            float4 s4 = *(const float4*)(bnsum + kg * 4);
            float4 q4 = *(const float4*)(bnsq + kg * 4);
            float4 g4 = *(const float4*)(bn_g + kg * 4);
            float4 t4 = *(const float4*)(bn_b + kg * 4);
            float mu;
            mu = s4.x * invN; a4.x = g4.x * rsqrtf(q4.x * invN - mu * mu + 1e-5f); b4.x = t4.x - mu * a4.x;
            mu = s4.y * invN; a4.y = g4.y * rsqrtf(q4.y * invN - mu * mu + 1e-5f); b4.y = t4.y - mu * a4.y;
            mu = s4.z * invN; a4.z = g4.z * rsqrtf(q4.z * invN - mu * mu + 1e-5f); b4.z = t4.z - mu * a4.z;
            mu = s4.w * invN; a4.w = g4.w * rsqrtf(q4.w * invN - mu * mu + 1e-5f); b4.w = t4.w - mu * a4.w;
        }
        half4v o4;
        o4[0] = (_Float16)(hv.x * a4.x + b4.x);
        o4[1] = (_Float16)(hv.y * a4.y + b4.y);
        o4[2] = (_Float16)(hv.z * a4.z + b4.z);
        o4[3] = (_Float16)(hv.w * a4.w + b4.w);
        *(half4v*)(&As[r * 72 + kg * 4]) = o4;
    }
    __syncthreads();

    int w = t >> 6, lane = t & 63;
    int y = w >> 2;
    const _Float16* Wm = Wt + (size_t)y * 16384;
    const float* bias  = y ? bdst : bsrc;
    _Float16* out      = y ? fdh : fsh;
    int n16 = lane & 15, qd = lane >> 4;
    int cw = (w & 3) * 64;
    f32x4 acc[4][4];
#pragma unroll
    for (int mt = 0; mt < 4; mt++)
#pragma unroll
        for (int nt = 0; nt < 4; nt++) acc[mt][nt] = (f32x4)(0.f);
    float bv[4];
#pragma unroll
    for (int nt = 0; nt < 4; nt++) bv[nt] = bias[cw + nt * 16 + n16];

#pragma unroll
    for (int kk = 0; kk < 2; kk++) {
        half8 af[4], bf[4];
#pragma unroll
        for (int mt = 0; mt < 4; mt++)
            af[mt] = *(const half8*)(&As[(mt * 16 + n16) * 72 + kk * 32 + qd * 8]);
#pragma unroll
        for (int nt = 0; nt < 4; nt++)
            bf[nt] = *(const half8*)(Wm + (size_t)(cw + nt * 16 + n16) * 64 + kk * 32 + qd * 8);
#pragma unroll
        for (int mt = 0; mt < 4; mt++)
#pragma unroll
            for (int nt = 0; nt < 4; nt++)
                acc[mt][nt] = __builtin_amdgcn_mfma_f32_16x16x32_f16(af[mt], bf[nt], acc[mt][nt], 0, 0, 0);
    }
#pragma unroll
    for (int mt = 0; mt < 4; mt++) {
#pragma unroll
        for (int i = 0; i < 4; i++) {
            int gr = row0 + mt * 16 + qd * 4 + i;
            if (gr < N) {
#pragma unroll
                for (int nt = 0; nt < 4; nt++)
                    out[(size_t)gr * 256 + cw + nt * 16 + n16] = (_Float16)(acc[mt][nt][i] + bv[nt]);
            }
        }
    }
}

// ---------------- fused GATv2 edge phase: wave per dst node ----------------

__global__ void __launch_bounds__(256) gat_kernel(
    const _Float16* __restrict__ fsh, const _Float16* __restrict__ fdh,
    const _Float16* __restrict__ att16,
    const int* __restrict__ row_ptr, const int* __restrict__ degv,
    const int* __restrict__ col_src,
    float* __restrict__ hmean, int N)
{
    int wid = (blockIdx.x << 2) + (threadIdx.x >> 6);
    if (wid >= N) return;
    int lane = threadIdx.x & 63;
    int e2 = lane >> 5;
    int d8 = lane & 31;
    int rs = row_ptr[wid];
    int deg = degv[wid];
    const int* cs = col_src + rs;
    const _Float16* fsb = fsh + d8 * 8;

    half8 fdv = *(const half8*)(fdh + (size_t)wid * 256 + d8 * 8);
    half8 att = *(const half8*)(att16 + (d8 >> 3) * 64 + (d8 & 7) * 8);
    half8 k02;
#pragma unroll
    for (int j = 0; j < 8; j++) k02[j] = (_Float16)0.2f;

    float acc[8];
#pragma unroll
    for (int j = 0; j < 8; j++) acc[j] = 0.f;
    float l = 0.f;

    auto body = [&](half8 fv) {
        half8 x = fv + fdv;
        half8 lx = __builtin_elementwise_max(x, x * k02);
        float p = 0.f;
#ifdef USE_FDOT2
#pragma unroll
        for (int j = 0; j < 4; j++) {
            half2v a2 = { lx[2 * j], lx[2 * j + 1] };
            half2v b2 = { att[2 * j], att[2 * j + 1] };
            p = __builtin_amdgcn_fdot2(a2, b2, p, false);
        }
#else
#pragma unroll
        for (int j = 0; j < 8; j++) p = fmaf((float)lx[j], (float)att[j], p);
#endif
        p = dpp_sum8(p);
        float e = EX2(p);            // att pre-scaled by log2(e)
        l += e;
#pragma unroll
        for (int j = 0; j < 8; j++) acc[j] = fmaf(e, (float)fv[j], acc[j]);
    };

    int deg8 = deg & ~7;
    int4 nsv;
    if (deg8 > 0) nsv = *(const int4*)(cs + 4 * e2);   // 16B-aligned (padded CSR)
    for (int i = 0; i < deg8; i += 8) {
        int4 sv = nsv;
        if (i + 8 < deg8) nsv = *(const int4*)(cs + i + 8 + 4 * e2);
        half8 f0 = *(const half8*)(fsb + (size_t)(unsigned)sv.x);
        half8 f1 = *(const half8*)(fsb + (size_t)(unsigned)sv.y);
        body(f0);
        half8 f2 = *(const half8*)(fsb + (size_t)(unsigned)sv.z);
        body(f1);
        half8 f3 = *(const half8*)(fsb + (size_t)(unsigned)sv.w);
        body(f2);
        body(f3);
    }
    for (int idx = deg8 + e2; idx < deg; idx += 2) {
        int s = cs[idx];
        half8 fv = *(const half8*)(fsb + (size_t)(unsigned)s);
        body(fv);
    }

    l += __shfl_xor(l, 32);
#pragma unroll
    for (int j = 0; j < 8; j++) acc[j] += __shfl_xor(acc[j], 32);

    float inv = (l > 0.f) ? 0.25f / l : 0.f;   // head-mean folded
    float m[8];
#pragma unroll
    for (int j = 0; j < 8; j++) m[j] = fmaxf(acc[j] * inv, 0.f);
#pragma unroll
    for (int j = 0; j < 8; j++) {
        m[j] += __shfl_xor(m[j], 8);
        m[j] += __shfl_xor(m[j], 16);
    }
    if (lane < 8) {
        float4 o0 = make_float4(m[0], m[1], m[2], m[3]);
        float4 o1 = make_float4(m[4], m[5], m[6], m[7]);
        *(float4*)(hmean + (size_t)wid * 64 + d8 * 8) = o0;
        *(float4*)(hmean + (size_t)wid * 64 + d8 * 8 + 4) = o1;
    }
}

// ---------------- BN stats + graph segment sums ----------------

__global__ void __launch_bounds__(256) stats_kernel(
    const float* __restrict__ hmean, const int* __restrict__ gid,
    float* __restrict__ bnsum, float* __restrict__ bnsumsq,
    float* __restrict__ S, int N)
{
    __shared__ float bs[4][64], bq[4][64];
    int t = threadIdx.x, lane = t & 63, w = t >> 6;
    int wglobal = blockIdx.x * 4 + w;
    int chunk = (N + 511) >> 9;
    int n0 = wglobal * chunk;
    int n1 = min(n0 + chunk, N);
    float sum = 0.f, sq = 0.f, run = 0.f;
    int cur = -1;
    for (int n = n0; n < n1; n++) {
        float v = hmean[(size_t)n * 64 + lane];
        int g = gid[n];
        if (g != cur) {
            if (cur >= 0) atomicAdd(&S[cur * 64 + lane], run);
            run = 0.f;
            cur = g;
        }
        run += v;
        sum += v;
        sq = fmaf(v, v, sq);
    }
    if (cur >= 0) atomicAdd(&S[cur * 64 + lane], run);
    bs[w][lane] = sum;
    bq[w][lane] = sq;
    __syncthreads();
    if (w == 0) {
        float s2 = bs[0][lane] + bs[1][lane] + bs[2][lane] + bs[3][lane];
        float q2 = bq[0][lane] + bq[1][lane] + bq[2][lane] + bq[3][lane];
        atomicAdd(&bnsum[lane], s2);
        atomicAdd(&bnsumsq[lane], q2);
    }
}

// ------- tail: pooled l2 (128 parallel blocks) + last-block head (small serial epilogue) ----

__global__ void __launch_bounds__(256) tail_kernel(
    const float* __restrict__ bnsum2, const float* __restrict__ bnsq2,
    const float* __restrict__ S2, const int* __restrict__ cntg,
    const float* __restrict__ bn_g2, const float* __restrict__ bn_b2,
    const float* __restrict__ lpW2, const float* __restrict__ lpb2,
    float* __restrict__ q, float* __restrict__ qsum, float* __restrict__ qsq,
    const float* __restrict__ lpg, const float* __restrict__ lpbt,
    const float* __restrict__ blW, const float* __restrict__ blb,
    const float* __restrict__ blg, const float* __restrict__ blbt,
    const float* __restrict__ llW, const float* __restrict__ llb,
    const float* __restrict__ llg, const float* __restrict__ llbt,
    int* __restrict__ done, float* __restrict__ out, int N)
{
    __shared__ float sv[64];
    __shared__ float partial4[4][64];
    __shared__ int amLast;
    int t = threadIdx.x;
    int g = blockIdx.x;
    float invN = 1.f / (float)N;

    // ---- pooled layer-2 for graph g (identical math to R9 pooled_a) ----
    if (t < 64) {
        float mu = bnsum2[t] * invN;
        float var = bnsq2[t] * invN - mu * mu;
        float aa = bn_g2[t] * rsqrtf(var + 1e-5f);
        float bb = bn_b2[t] - mu * aa;
        sv[t] = aa * S2[g * 64 + t] + bb * (float)cntg[g];
    }
    __syncthreads();
    {
        int f = t & 63, kc = t >> 6;
        float acc = 0.f;
#pragma unroll
        for (int k = kc * 16; k < kc * 16 + 16; k++)
            acc = fmaf(sv[k], lpW2[k * 64 + f], acc);
        partial4[kc][f] = acc;
        __syncthreads();
        if (t < 64) {
            float v = partial4[0][t] + partial4[1][t] + partial4[2][t] + partial4[3][t] + lpb2[t];
            v = fmaxf(v, 0.f);
            q[2 * 8192 + g * 64 + t] = v;
            atomicAdd(&qsum[128 + t], v);
            atomicAdd(&qsq[128 + t], v * v);
        }
    }
    __syncthreads();
    __threadfence();
    if (t == 0) amLast = (atomicAdd(done, 1) == (int)gridDim.x - 1);
    __syncthreads();
    if (!amLast) return;

    // ---- last block: head GEMM over all 128 graphs + BN + ll + log_softmax ----
    __shared__ float hn[128][65];
    __shared__ float cat4[4][192];
    __shared__ float qa[192], qb[192];
    __shared__ float rs[4][64], rq[4][64];
    __shared__ float muh[64], sch[64];
    __shared__ float sW[640];
    __shared__ float ph[128][12];
    __shared__ float mj[16], scj[16];

    if (t < 192) {
        float mu = vload(&qsum[t]) * (1.f / 128.f);
        float var = vload(&qsq[t]) * (1.f / 128.f) - mu * mu;
        float sc = lpg[t] * rsqrtf(var + 1e-5f);
        qa[t] = sc;
        qb[t] = lpbt[t] - mu * sc;
    }
    for (int i = t; i < 640; i += 256) sW[i] = llW[i];
    __syncthreads();

    int gc = t >> 6, f = t & 63;
    float hs = 0.f, hq = 0.f;
    for (int g0 = 0; g0 < 128; g0 += 4) {
        for (int i = t; i < 768; i += 256) {
            int gg = i / 192, k = i - gg * 192;
            int ci = k >> 6, ff = k & 63;
            cat4[gg][k] = vload(&q[ci * 8192 + (g0 + gg) * 64 + ff]) * qa[k] + qb[k];
        }
        __syncthreads();
        float s = blb[f];
#pragma unroll 16
        for (int k = 0; k < 192; k++)
            s = fmaf(cat4[gc][k], blW[k * 64 + f], s);
        s = fmaxf(s, 0.f);
        hn[g0 + gc][f] = s;
        hs += s;
        hq = fmaf(s, s, hq);
        __syncthreads();
    }
    rs[gc][f] = hs;
    rq[gc][f] = hq;
    __syncthreads();
    if (t < 64) {
        float m = (rs[0][t] + rs[1][t] + rs[2][t] + rs[3][t]) * (1.f / 128.f);
        float v = (rq[0][t] + rq[1][t] + rq[2][t] + rq[3][t]) * (1.f / 128.f) - m * m;
        muh[t] = m;
        sch[t] = blg[t] / sqrtf(v + 1e-5f);
    }
    __syncthreads();
    for (int i = t; i < 8192; i += 256) {
        int gg = i >> 6, ff = i & 63;
        float v = (hn[gg][ff] - muh[ff]) * sch[ff] + blbt[ff];
        out[1280 + i] = v;          // output 1: pooled_hh
        hn[gg][ff] = v;
    }
    __syncthreads();
    for (int i = t; i < 1280; i += 256) {
        int gg = i / 10, j = i - gg * 10;
        float s = llb[j];
#pragma unroll 8
        for (int k = 0; k < 64; k++) s = fmaf(hn[gg][k], sW[k * 10 + j], s);
        ph[gg][j] = fmaxf(s, 0.f);
    }
    __syncthreads();
    if (t < 10) {
        float m = 0.f;
        for (int gg = 0; gg < 128; gg++) m += ph[gg][t];
        m *= (1.f / 128.f);
        float v = 0.f;
        for (int gg = 0; gg < 128; gg++) { float d = ph[gg][t] - m; v = fmaf(d, d, v); }
        v *= (1.f / 128.f);
        mj[t] = m;
        scj[t] = llg[t] / sqrtf(v + 1e-5f);
    }
    __syncthreads();
    if (t < 128) {
        float vals[10];
        float mx = -1e30f;
        for (int j = 0; j < 10; j++) {
            vals[j] = (ph[t][j] - mj[j]) * scj[j] + llbt[j];
            mx = fmaxf(mx, vals[j]);
        }
        float se = 0.f;
        for (int j = 0; j < 10; j++) se += __expf(vals[j] - mx);
        float lse = logf(se) + mx;
        for (int j = 0; j < 10; j++) out[t * 10 + j] = vals[j] - lse;   // output 0
    }
}

// ---------------- launcher ----------------

extern "C" void kernel_launch(void* const* d_in, const int* in_sizes, int n_in,
                              void* d_out, int out_size, void* d_ws, size_t ws_size,
                              hipStream_t stream)
{
    const float* feat = (const float*)d_in[0];
    const float* Wsrc = (const float*)d_in[1];
    const float* bsrc = (const float*)d_in[2];
    const float* Wdst = (const float*)d_in[3];
    const float* bdst = (const float*)d_in[4];
    const float* attn = (const float*)d_in[5];
    const float* bn_g = (const float*)d_in[6];
    const float* bn_b = (const float*)d_in[7];
    const float* lpW  = (const float*)d_in[8];
    const float* lpb  = (const float*)d_in[9];
    const float* lpg  = (const float*)d_in[10];
    const float* lpbt = (const float*)d_in[11];
    const float* blW  = (const float*)d_in[12];
    const float* blb  = (const float*)d_in[13];
    const float* blg  = (const float*)d_in[14];
    const float* blbt = (const float*)d_in[15];
    const float* llW  = (const float*)d_in[16];
    const float* llb  = (const float*)d_in[17];
    const float* llg  = (const float*)d_in[18];
    const float* llbt = (const float*)d_in[19];
    const int* srcp = (const int*)d_in[20];
    const int* dstp = (const int*)d_in[21];
    const int* gidp = (const int*)d_in[22];
    float* out = (float*)d_out;

    int N = in_sizes[0] / 64;
    int E = in_sizes[20];
    int nb = (N + 1023) / 1024;

    // workspace (same offsets as R9; hsum slot reused as done counter)
    float* wsf = (float*)d_ws;
    _Float16* fsh = (_Float16*)wsf;                       // N*256 f16
    _Float16* fdh = (_Float16*)(wsf + (size_t)N * 128);   // N*256 f16
    float* hmean = wsf + (size_t)N * 256;            // N*64
    float* q     = hmean + (size_t)N * 64;           // 3*8192
    float* hh    = q + 24576;                        // 8192 (unused, kept for layout)
    _Float16* Wt16  = (_Float16*)(hh + 8192);        // 6*16384 f16
    _Float16* att16 = (_Float16*)(hh + 8192 + 49152);// 768 f16
    float* zstart = hh + 8192 + 49152 + 384;
    float* bnsum = zstart;                           // 3*64
    float* bnsq  = bnsum + 192;                      // 3*64
    float* qsum  = bnsq + 192;                       // 3*64
    float* qsq   = qsum + 192;                       // 3*64
    int*   done  = (int*)(qsq + 192);                // 1 (in zeroed span)
    float* hsq   = (float*)(done + 64);              // pad (keeps 16B alignment)
    float* S     = hsq + 64;                         // 3*8192
    int* deg     = (int*)(S + 24576);                // N
    int* gbase   = deg + N;                          // 4 (padded)
    int* zend    = gbase + 4;
    int* cntg    = zend;                             // 128
    int* gstart  = cntg + 128;                       // 128
    int* row_ptr = gstart + 128;                     // N
    int* col_src = row_ptr + N;                      // E + 3N + 64 (padded rows)
    int* pos     = col_src + E + 3 * N + 64;         // E

    size_t zbytes = (size_t)((char*)zend - (char*)zstart);
    hipMemsetAsync(zstart, 0, zbytes, stream);

    int hbBlocks = ((E > N ? E : N) + 255) / 256;
    hipLaunchKernelGGL(wcvt_hb_kernel, dim3(24 + hbBlocks), dim3(256), 0, stream,
                       Wsrc, Wdst, attn, Wt16, att16, dstp, deg, pos, gidp, gstart, N, E);
    hipLaunchKernelGGL(rowptr_kernel, dim3(nb), dim3(256), 0, stream,
                       deg, row_ptr, gbase, gstart, cntg, N);

    int gemmBlocks = (N + 63) / 64;
    int scatBlocks = (E + 511) / 512;
    for (int l = 0; l < 3; l++) {
        const float* hsrcp = (l == 0) ? feat : hmean;
        int sb = (l == 0) ? scatBlocks : 0;   // layer-0 gemm grid also scatters
        int pb = (l >= 1) ? NG : 0;           // layer>=1 gemm grid also runs pooled(l-1)
        hipLaunchKernelGGL(gemm_kernel, dim3(gemmBlocks + sb + pb), dim3(512), 0, stream,
                           hsrcp, bnsum + (l - 1) * 64, bnsq + (l - 1) * 64,
                           bn_g + (l - 1) * 64, bn_b + (l - 1) * 64,
                           (l == 0) ? 1 : 0, 1.f / (float)N,
                           Wt16 + (size_t)l * 32768, bsrc + l * 256, bdst + l * 256,
                           fsh, fdh, N, gemmBlocks, sb,
                           srcp, dstp, row_ptr, pos, col_src, E,
                           S + (l - 1) * 8192, cntg,
                           lpW + (size_t)(l - 1) * 4096, lpb + (l - 1) * 64,
                           q + (l - 1) * 8192, qsum + (l - 1) * 64, qsq + (l - 1) * 64);
        hipLaunchKernelGGL(gat_kernel, dim3((N + 3) / 4), dim3(256), 0, stream,
                           fsh, fdh, att16 + l * 256, row_ptr, deg, col_src, hmean, N);
        hipLaunchKernelGGL(stats_kernel, dim3(128), dim3(256), 0, stream,
                           hmean, gidp, bnsum + l * 64, bnsq + l * 64, S + l * 8192, N);
    }
    hipLaunchKernelGGL(tail_kernel, dim3(NG), dim3(256), 0, stream,
                       bnsum + 2 * 64, bnsq + 2 * 64, S + 2 * 8192, cntg,
                       bn_g + 2 * 64, bn_b + 2 * 64,
                       lpW + (size_t)2 * 4096, lpb + 2 * 64,
                       q, qsum, qsq, lpg, lpbt, blW, blb, blg, blbt,
                       llW, llb, llg, llbt, done, out, N);
}

// Round 13
// 526.115 us; speedup vs baseline: 12.7394x; 1.1546x over previous
//
#include <hip/hip_runtime.h>
#include <cmath>

#define NH 4
#define NG 128

typedef _Float16 half8 __attribute__((ext_vector_type(8)));
typedef _Float16 half4v __attribute__((ext_vector_type(4)));
typedef _Float16 half2v __attribute__((ext_vector_type(2)));
typedef float f32x4 __attribute__((ext_vector_type(4)));

#if defined(__has_builtin)
# if __has_builtin(__builtin_amdgcn_fdot2)
#  define USE_FDOT2 1
# endif
# if __has_builtin(__builtin_amdgcn_update_dpp)
#  define USE_DPP 1
# endif
# if __has_builtin(__builtin_amdgcn_exp2f)
#  define EX2(x) __builtin_amdgcn_exp2f(x)
# endif
#endif
#ifndef EX2
# define EX2(x) exp2f(x)
#endif

__device__ inline float vload(const float* p) { return *(volatile const float*)p; }

__device__ inline float dpp_sum8(float p) {
#ifdef USE_DPP
    int pi = __builtin_bit_cast(int, p);
    int a = __builtin_amdgcn_update_dpp(0, pi, 0xB1, 0xF, 0xF, true);
    p += __builtin_bit_cast(float, a);
    pi = __builtin_bit_cast(int, p);
    a = __builtin_amdgcn_update_dpp(0, pi, 0x4E, 0xF, 0xF, true);
    p += __builtin_bit_cast(float, a);
    pi = __builtin_bit_cast(int, p);
    a = __builtin_amdgcn_update_dpp(0, pi, 0x141, 0xF, 0xF, true);
    p += __builtin_bit_cast(float, a);
    return p;
#else
    p += __shfl_xor(p, 1); p += __shfl_xor(p, 2); p += __shfl_xor(p, 4);
    return p;
#endif
}

// ------- fused: W->Wt[c][k] f16 (24 tile-blocks) + hist/pos + graph bounds -------

__global__ void __launch_bounds__(256) wcvt_hb_kernel(
    const float* __restrict__ Wsrc, const float* __restrict__ Wdst,
    const float* __restrict__ attn,
    _Float16* __restrict__ Wt, _Float16* __restrict__ att16,
    const int* __restrict__ dst, int* __restrict__ deg, int* __restrict__ pos,
    const int* __restrict__ gid, int* __restrict__ gstart, int N, int E)
{
    int t = threadIdx.x;
    if (blockIdx.x < 24) {
        __shared__ _Float16 lt[64 * 68];
        int b = blockIdx.x;
        int mat = b >> 2, ct = b & 3;
        int c0 = ct * 64;
        const float* W = ((mat & 1) ? Wdst : Wsrc) + (size_t)(mat >> 1) * 16384;
        _Float16* o = Wt + (size_t)mat * 16384;
#pragma unroll
        for (int i = 0; i < 16; i++) {
            int flat = i * 256 + t;
            int k = flat >> 6, c = flat & 63;
            lt[c * 68 + k] = (_Float16)W[k * 256 + c0 + c];
        }
        __syncthreads();
#pragma unroll
        for (int i = 0; i < 16; i++) {
            int flat = i * 256 + t;
            int c = flat >> 6, k = flat & 63;
            o[(size_t)(c0 + c) * 64 + k] = lt[c * 68 + k];
        }
        if (b == 0)
            for (int i = t; i < 3 * 256; i += 256)
                att16[i] = (_Float16)(attn[i] * 1.44269504f);   // fold log2(e)
        return;
    }
    int i = (blockIdx.x - 24) * 256 + t;
    if (i < E) pos[i] = atomicAdd(&deg[dst[i]], 1);
    if (i < N) {
        int a = gid[i];
        if (i == 0)
            for (int g = 0; g <= a; g++) gstart[g] = 0;
        int b2 = (i + 1 < N) ? gid[i + 1] : NG;
        for (int g = a + 1; g <= b2 && g < NG; g++) gstart[g] = i + 1;
    }
}

// single-dispatch row offsets, rows padded to multiples of 4 (for int4 col_src loads)
__global__ void __launch_bounds__(256) rowptr_kernel(const int* __restrict__ deg,
                                                     int* __restrict__ row_ptr,
                                                     int* __restrict__ gbase,
                                                     const int* __restrict__ gstart,
                                                     int* __restrict__ cntg, int N) {
    __shared__ int red[256];
    __shared__ int base_s;
    int t = threadIdx.x;
    int base = blockIdx.x * 1024 + t * 4;
    int dp[4];
    int s = 0;
#pragma unroll
    for (int j = 0; j < 4; j++) {
        int i = base + j;
        int d = (i < N) ? deg[i] : 0;
        dp[j] = (d + 3) & ~3;
        s += dp[j];
    }
    red[t] = s;
    __syncthreads();
    for (int off = 1; off < 256; off <<= 1) {
        int v = (t >= off) ? red[t - off] : 0;
        __syncthreads();
        red[t] += v;
        __syncthreads();
    }
    if (t == 255) base_s = atomicAdd(gbase, red[255]);
    __syncthreads();
    int excl = red[t] - s + base_s;
#pragma unroll
    for (int j = 0; j < 4; j++) {
        int i = base + j;
        if (i < N) row_ptr[i] = excl;
        excl += dp[j];
    }
    if (blockIdx.x == 0 && t < NG) {
        int s1 = (t == NG - 1) ? N : gstart[t + 1];
        cntg[t] = s1 - gstart[t];
    }
}

// ------- fused BN-affine + dual GEMM (f16 MFMA); extra roles: scatter, pooled MLP -------

__global__ void __launch_bounds__(512) gemm_kernel(
    const float* __restrict__ h,
    const float* __restrict__ bnsum, const float* __restrict__ bnsq,
    const float* __restrict__ bn_g, const float* __restrict__ bn_b,
    int isl0, float invN,
    const _Float16* __restrict__ Wt,
    const float* __restrict__ bsrc, const float* __restrict__ bdst,
    _Float16* __restrict__ fsh, _Float16* __restrict__ fdh, int N,
    int gemmBlocks, int scatBlocks,
    const int* __restrict__ src, const int* __restrict__ dst,
    const int* __restrict__ row_ptr, const int* __restrict__ pos,
    int* __restrict__ col_src, int E,
    const float* __restrict__ S, const int* __restrict__ cntg,
    const float* __restrict__ plpW, const float* __restrict__ plpb,
    float* __restrict__ q, float* __restrict__ qsum, float* __restrict__ qsq)
{
    int t = threadIdx.x;
    if (blockIdx.x >= gemmBlocks) {
        int pb = blockIdx.x - gemmBlocks - scatBlocks;
        if (pb < 0) {                         // scatter role (atomic-free)
            int e = (blockIdx.x - gemmBlocks) * 512 + t;
            if (e < E) {
                int d = dst[e];
                col_src[row_ptr[d] + pos[e]] = src[e] << 8;   // f16-element row offset
            }
            return;
        }
        // pooled role: graph pb, layer l-1
        __shared__ float sv[64];
        __shared__ float partial[8][64];
        if (t < 64) {
            float mu = bnsum[t] * invN;
            float var = bnsq[t] * invN - mu * mu;
            float aa = bn_g[t] * rsqrtf(var + 1e-5f);
            float bb = bn_b[t] - mu * aa;
            sv[t] = aa * S[pb * 64 + t] + bb * (float)cntg[pb];
        }
        __syncthreads();
        int f = t & 63, kc = t >> 6;
        float acc = 0.f;
#pragma unroll
        for (int k = kc * 8; k < kc * 8 + 8; k++)
            acc = fmaf(sv[k], plpW[k * 64 + f], acc);
        partial[kc][f] = acc;
        __syncthreads();
        if (t < 64) {
            float v = plpb[t];
#pragma unroll
            for (int j = 0; j < 8; j++) v += partial[j][t];
            v = fmaxf(v, 0.f);
            q[pb * 64 + t] = v;
            atomicAdd(&qsum[t], v);
            atomicAdd(&qsq[t], v * v);
        }
        return;
    }
    __shared__ _Float16 As[64 * 72];
    int row0 = blockIdx.x * 64;

#pragma unroll
    for (int i = 0; i < 2; i++) {
        int flat = i * 512 + t;
        int r = flat >> 4, kg = flat & 15;
        int gr = row0 + r;
        float4 hv = make_float4(0.f, 0.f, 0.f, 0.f);
        if (gr < N) hv = *(const float4*)(h + (size_t)gr * 64 + kg * 4);
        float4 a4, b4;
        if (isl0) {
            a4 = make_float4(1.f, 1.f, 1.f, 1.f);
            b4 = make_float4(0.f, 0.f, 0.f, 0.f);
        } else {
            float4 s4 = *(const float4*)(bnsum + kg * 4);
            float4 q4 = *(const float4*)(bnsq + kg * 4);
            float4 g4 = *(const float4*)(bn_g + kg * 4);
            float4 t4 = *(const float4*)(bn_b + kg * 4);
            float mu;
            mu = s4.x * invN; a4.x = g4.x * rsqrtf(q4.x * invN - mu * mu + 1e-5f); b4.x = t4.x - mu * a4.x;
            mu = s4.y * invN; a4.y = g4.y * rsqrtf(q4.y * invN - mu * mu + 1e-5f); b4.y = t4.y - mu * a4.y;
            mu = s4.z * invN; a4.z = g4.z * rsqrtf(q4.z * invN - mu * mu + 1e-5f); b4.z = t4.z - mu * a4.z;
            mu = s4.w * invN; a4.w = g4.w * rsqrtf(q4.w * invN - mu * mu + 1e-5f); b4.w = t4.w - mu * a4.w;
        }
        half4v o4;
        o4[0] = (_Float16)(hv.x * a4.x + b4.x);
        o4[1] = (_Float16)(hv.y * a4.y + b4.y);
        o4[2] = (_Float16)(hv.z * a4.z + b4.z);
        o4[3] = (_Float16)(hv.w * a4.w + b4.w);
        *(half4v*)(&As[r * 72 + kg * 4]) = o4;
    }
    __syncthreads();

    int w = t >> 6, lane = t & 63;
    int y = w >> 2;
    const _Float16* Wm = Wt + (size_t)y * 16384;
    const float* bias  = y ? bdst : bsrc;
    _Float16* out      = y ? fdh : fsh;
    int n16 = lane & 15, qd = lane >> 4;
    int cw = (w & 3) * 64;
    f32x4 acc[4][4];
#pragma unroll
    for (int mt = 0; mt < 4; mt++)
#pragma unroll
        for (int nt = 0; nt < 4; nt++) acc[mt][nt] = (f32x4)(0.f);
    float bv[4];
#pragma unroll
    for (int nt = 0; nt < 4; nt++) bv[nt] = bias[cw + nt * 16 + n16];

#pragma unroll
    for (int kk = 0; kk < 2; kk++) {
        half8 af[4], bf[4];
#pragma unroll
        for (int mt = 0; mt < 4; mt++)
            af[mt] = *(const half8*)(&As[(mt * 16 + n16) * 72 + kk * 32 + qd * 8]);
#pragma unroll
        for (int nt = 0; nt < 4; nt++)
            bf[nt] = *(const half8*)(Wm + (size_t)(cw + nt * 16 + n16) * 64 + kk * 32 + qd * 8);
#pragma unroll
        for (int mt = 0; mt < 4; mt++)
#pragma unroll
            for (int nt = 0; nt < 4; nt++)
                acc[mt][nt] = __builtin_amdgcn_mfma_f32_16x16x32_f16(af[mt], bf[nt], acc[mt][nt], 0, 0, 0);
    }
#pragma unroll
    for (int mt = 0; mt < 4; mt++) {
#pragma unroll
        for (int i = 0; i < 4; i++) {
            int gr = row0 + mt * 16 + qd * 4 + i;
            if (gr < N) {
#pragma unroll
                for (int nt = 0; nt < 4; nt++)
                    out[(size_t)gr * 256 + cw + nt * 16 + n16] = (_Float16)(acc[mt][nt][i] + bv[nt]);
            }
        }
    }
}

// ---------------- fused GATv2 edge phase: wave per dst node ----------------

__global__ void __launch_bounds__(256) gat_kernel(
    const _Float16* __restrict__ fsh, const _Float16* __restrict__ fdh,
    const _Float16* __restrict__ att16,
    const int* __restrict__ row_ptr, const int* __restrict__ degv,
    const int* __restrict__ col_src,
    float* __restrict__ hmean, int N)
{
    int wid = (blockIdx.x << 2) + (threadIdx.x >> 6);
    if (wid >= N) return;
    int lane = threadIdx.x & 63;
    int e2 = lane >> 5;
    int d8 = lane & 31;
    int rs = row_ptr[wid];
    int deg = degv[wid];
    const int* cs = col_src + rs;
    const _Float16* fsb = fsh + d8 * 8;

    half8 fdv = *(const half8*)(fdh + (size_t)wid * 256 + d8 * 8);
    half8 att = *(const half8*)(att16 + (d8 >> 3) * 64 + (d8 & 7) * 8);
    half8 k02;
#pragma unroll
    for (int j = 0; j < 8; j++) k02[j] = (_Float16)0.2f;

    float acc[8];
#pragma unroll
    for (int j = 0; j < 8; j++) acc[j] = 0.f;
    float l = 0.f;

    auto body = [&](half8 fv) {
        half8 x = fv + fdv;
        half8 lx = __builtin_elementwise_max(x, x * k02);
        float p = 0.f;
#ifdef USE_FDOT2
#pragma unroll
        for (int j = 0; j < 4; j++) {
            half2v a2 = { lx[2 * j], lx[2 * j + 1] };
            half2v b2 = { att[2 * j], att[2 * j + 1] };
            p = __builtin_amdgcn_fdot2(a2, b2, p, false);
        }
#else
#pragma unroll
        for (int j = 0; j < 8; j++) p = fmaf((float)lx[j], (float)att[j], p);
#endif
        p = dpp_sum8(p);
        float e = EX2(p);            // att pre-scaled by log2(e)
        l += e;
#pragma unroll
        for (int j = 0; j < 8; j++) acc[j] = fmaf(e, (float)fv[j], acc[j]);
    };

    int deg8 = deg & ~7;
    int4 nsv;
    if (deg8 > 0) nsv = *(const int4*)(cs + 4 * e2);   // 16B-aligned (padded CSR)
    for (int i = 0; i < deg8; i += 8) {
        int4 sv = nsv;
        if (i + 8 < deg8) nsv = *(const int4*)(cs + i + 8 + 4 * e2);
        half8 f0 = *(const half8*)(fsb + (size_t)(unsigned)sv.x);
        half8 f1 = *(const half8*)(fsb + (size_t)(unsigned)sv.y);
        body(f0);
        half8 f2 = *(const half8*)(fsb + (size_t)(unsigned)sv.z);
        body(f1);
        half8 f3 = *(const half8*)(fsb + (size_t)(unsigned)sv.w);
        body(f2);
        body(f3);
    }
    for (int idx = deg8 + e2; idx < deg; idx += 2) {
        int s = cs[idx];
        half8 fv = *(const half8*)(fsb + (size_t)(unsigned)s);
        body(fv);
    }

    l += __shfl_xor(l, 32);
#pragma unroll
    for (int j = 0; j < 8; j++) acc[j] += __shfl_xor(acc[j], 32);

    float inv = (l > 0.f) ? 0.25f / l : 0.f;   // head-mean folded
    float m[8];
#pragma unroll
    for (int j = 0; j < 8; j++) m[j] = fmaxf(acc[j] * inv, 0.f);
#pragma unroll
    for (int j = 0; j < 8; j++) {
        m[j] += __shfl_xor(m[j], 8);
        m[j] += __shfl_xor(m[j], 16);
    }
    if (lane < 8) {
        float4 o0 = make_float4(m[0], m[1], m[2], m[3]);
        float4 o1 = make_float4(m[4], m[5], m[6], m[7]);
        *(float4*)(hmean + (size_t)wid * 64 + d8 * 8) = o0;
        *(float4*)(hmean + (size_t)wid * 64 + d8 * 8 + 4) = o1;
    }
}

// ---------------- BN stats + graph segment sums ----------------

__global__ void __launch_bounds__(256) stats_kernel(
    const float* __restrict__ hmean, const int* __restrict__ gid,
    float* __restrict__ bnsum, float* __restrict__ bnsumsq,
    float* __restrict__ S, int N)
{
    __shared__ float bs[4][64], bq[4][64];
    int t = threadIdx.x, lane = t & 63, w = t >> 6;
    int wglobal = blockIdx.x * 4 + w;
    int chunk = (N + 511) >> 9;
    int n0 = wglobal * chunk;
    int n1 = min(n0 + chunk, N);
    float sum = 0.f, sq = 0.f, run = 0.f;
    int cur = -1;
    for (int n = n0; n < n1; n++) {
        float v = hmean[(size_t)n * 64 + lane];
        int g = gid[n];
        if (g != cur) {
            if (cur >= 0) atomicAdd(&S[cur * 64 + lane], run);
            run = 0.f;
            cur = g;
        }
        run += v;
        sum += v;
        sq = fmaf(v, v, sq);
    }
    if (cur >= 0) atomicAdd(&S[cur * 64 + lane], run);
    bs[w][lane] = sum;
    bq[w][lane] = sq;
    __syncthreads();
    if (w == 0) {
        float s2 = bs[0][lane] + bs[1][lane] + bs[2][lane] + bs[3][lane];
        float q2 = bq[0][lane] + bq[1][lane] + bq[2][lane] + bq[3][lane];
        atomicAdd(&bnsum[lane], s2);
        atomicAdd(&bnsumsq[lane], q2);
    }
}

// ---------------- pooled (standalone, layer 2) ----------------

__global__ void __launch_bounds__(256) pooled_a_kernel(
    const float* __restrict__ bnsum, const float* __restrict__ bnsumsq,
    const float* __restrict__ S, const int* __restrict__ cntg,
    const float* __restrict__ bn_g, const float* __restrict__ bn_b,
    const float* __restrict__ lpW, const float* __restrict__ lpb,
    float* __restrict__ q, float* __restrict__ qsum, float* __restrict__ qsq, int N)
{
    __shared__ float sv[64];
    __shared__ float partial[4][64];
    int g = blockIdx.x;
    int t = threadIdx.x;
    if (t < 64) {
        float mu = bnsum[t] / (float)N;
        float var = bnsumsq[t] / (float)N - mu * mu;
        float a = bn_g[t] / sqrtf(var + 1e-5f);
        float b = bn_b[t] - mu * a;
        sv[t] = a * S[g * 64 + t] + b * (float)cntg[g];
    }
    __syncthreads();
    int f = t & 63, kc = t >> 6;
    float acc = 0.f;
#pragma unroll
    for (int k = kc * 16; k < kc * 16 + 16; k++)
        acc = fmaf(sv[k], lpW[k * 64 + f], acc);
    partial[kc][f] = acc;
    __syncthreads();
    if (t < 64) {
        float v = partial[0][t] + partial[1][t] + partial[2][t] + partial[3][t] + lpb[t];
        v = fmaxf(v, 0.f);
        q[g * 64 + t] = v;
        atomicAdd(&qsum[t], v);
        atomicAdd(&qsq[t], v * v);
    }
}

// ------- head: on-the-fly q-BN + cat GEMM (128 parallel blocks); last block finishes -------

__global__ void __launch_bounds__(256) head_kernel(
    const float* __restrict__ q, const float* __restrict__ qsum, const float* __restrict__ qsq,
    const float* __restrict__ lpg, const float* __restrict__ lpbt,
    const float* __restrict__ blW, const float* __restrict__ blb,
    const float* __restrict__ blg, const float* __restrict__ blbt,
    const float* __restrict__ llW, const float* __restrict__ llb,
    const float* __restrict__ llg, const float* __restrict__ llbt,
    float* __restrict__ hh, float* __restrict__ hsum, float* __restrict__ hsq,
    int* __restrict__ done, float* __restrict__ out)
{
    __shared__ float cat[192];
    __shared__ float partial[4][64];
    __shared__ int amLast;
    int g = blockIdx.x;
    int t = threadIdx.x;
    if (t < 192) {
        int ci = t >> 6, f = t & 63;
        float mu = qsum[ci * 64 + f] * (1.f / 128.f);
        float var = qsq[ci * 64 + f] * (1.f / 128.f) - mu * mu;
        float sc = lpg[ci * 64 + f] * rsqrtf(var + 1e-5f);
        cat[t] = (q[ci * 8192 + g * 64 + f] - mu) * sc + lpbt[ci * 64 + f];
    }
    __syncthreads();
    int f = t & 63, kc = t >> 6;
    float acc = 0.f;
#pragma unroll
    for (int k = kc * 48; k < kc * 48 + 48; k++)
        acc = fmaf(cat[k], blW[k * 64 + f], acc);
    partial[kc][f] = acc;
    __syncthreads();
    if (t < 64) {
        float v = partial[0][t] + partial[1][t] + partial[2][t] + partial[3][t] + blb[t];
        v = fmaxf(v, 0.f);
        hh[g * 64 + t] = v;
        atomicAdd(&hsum[t], v);
        atomicAdd(&hsq[t], v * v);
    }
    __syncthreads();
    __threadfence();
    if (t == 0) amLast = (atomicAdd(done, 1) == (int)gridDim.x - 1);
    __syncthreads();
    if (!amLast) return;

    // ---- last block: small finish (BN + 64->10 linear + BN + log_softmax) ----
    __shared__ float hn[128][65];
    __shared__ float ph[128][12];
    __shared__ float mu[64], sc[64];
    __shared__ float mj[12], scj[12];
    __shared__ float sW[640];
    if (t < 64) {
        float m = vload(&hsum[t]) * (1.f / 128.f);
        float v = vload(&hsq[t]) * (1.f / 128.f) - m * m;
        mu[t] = m;
        sc[t] = blg[t] / sqrtf(v + 1e-5f);
    }
    for (int i = t; i < 640; i += 256) sW[i] = llW[i];
    __syncthreads();
    for (int i = t; i < 8192; i += 256) {
        int gg = i >> 6, ff = i & 63;
        float v = (vload(&hh[i]) - mu[ff]) * sc[ff] + blbt[ff];
        out[1280 + i] = v;          // output 1: pooled_hh
        hn[gg][ff] = v;
    }
    __syncthreads();
    for (int i = t; i < 1280; i += 256) {
        int gg = i / 10, j = i - gg * 10;
        float s = llb[j];
#pragma unroll 8
        for (int k = 0; k < 64; k++) s = fmaf(hn[gg][k], sW[k * 10 + j], s);
        ph[gg][j] = fmaxf(s, 0.f);
    }
    __syncthreads();
    if (t < 10) {
        float m = 0.f;
        for (int gg = 0; gg < 128; gg++) m += ph[gg][t];
        m *= (1.f / 128.f);
        float v = 0.f;
        for (int gg = 0; gg < 128; gg++) { float d = ph[gg][t] - m; v = fmaf(d, d, v); }
        v *= (1.f / 128.f);
        mj[t] = m;
        scj[t] = llg[t] / sqrtf(v + 1e-5f);
    }
    __syncthreads();
    if (t < 128) {
        float vals[10];
        float mx = -1e30f;
        for (int j = 0; j < 10; j++) {
            vals[j] = (ph[t][j] - mj[j]) * scj[j] + llbt[j];
            mx = fmaxf(mx, vals[j]);
        }
        float se = 0.f;
        for (int j = 0; j < 10; j++) se += __expf(vals[j] - mx);
        float lse = logf(se) + mx;
        for (int j = 0; j < 10; j++) out[t * 10 + j] = vals[j] - lse;   // output 0
    }
}

// ---------------- launcher ----------------

extern "C" void kernel_launch(void* const* d_in, const int* in_sizes, int n_in,
                              void* d_out, int out_size, void* d_ws, size_t ws_size,
                              hipStream_t stream)
{
    const float* feat = (const float*)d_in[0];
    const float* Wsrc = (const float*)d_in[1];
    const float* bsrc = (const float*)d_in[2];
    const float* Wdst = (const float*)d_in[3];
    const float* bdst = (const float*)d_in[4];
    const float* attn = (const float*)d_in[5];
    const float* bn_g = (const float*)d_in[6];
    const float* bn_b = (const float*)d_in[7];
    const float* lpW  = (const float*)d_in[8];
    const float* lpb  = (const float*)d_in[9];
    const float* lpg  = (const float*)d_in[10];
    const float* lpbt = (const float*)d_in[11];
    const float* blW  = (const float*)d_in[12];
    const float* blb  = (const float*)d_in[13];
    const float* blg  = (const float*)d_in[14];
    const float* blbt = (const float*)d_in[15];
    const float* llW  = (const float*)d_in[16];
    const float* llb  = (const float*)d_in[17];
    const float* llg  = (const float*)d_in[18];
    const float* llbt = (const float*)d_in[19];
    const int* srcp = (const int*)d_in[20];
    const int* dstp = (const int*)d_in[21];
    const int* gidp = (const int*)d_in[22];
    float* out = (float*)d_out;

    int N = in_sizes[0] / 64;
    int E = in_sizes[20];
    int nb = (N + 1023) / 1024;

    // workspace (R9 layout; done counter lives in the zeroed span)
    float* wsf = (float*)d_ws;
    _Float16* fsh = (_Float16*)wsf;                       // N*256 f16
    _Float16* fdh = (_Float16*)(wsf + (size_t)N * 128);   // N*256 f16
    float* hmean = wsf + (size_t)N * 256;            // N*64
    float* q     = hmean + (size_t)N * 64;           // 3*8192
    float* hh    = q + 24576;                        // 8192
    _Float16* Wt16  = (_Float16*)(hh + 8192);        // 6*16384 f16
    _Float16* att16 = (_Float16*)(hh + 8192 + 49152);// 768 f16
    float* zstart = hh + 8192 + 49152 + 384;
    float* bnsum = zstart;                           // 3*64
    float* bnsq  = bnsum + 192;                      // 3*64
    float* qsum  = bnsq + 192;                       // 3*64
    float* qsq   = qsum + 192;                       // 3*64
    float* hsum  = qsq + 192;                        // 64
    float* hsq   = hsum + 64;                        // 64
    int*   done  = (int*)(hsq + 64);                 // 4
    float* S     = (float*)(done + 4);               // 3*8192
    int* deg     = (int*)(S + 24576);                // N
    int* gbase   = deg + N;                          // 4 (padded)
    int* zend    = gbase + 4;
    int* cntg    = zend;                             // 128
    int* gstart  = cntg + 128;                       // 128
    int* row_ptr = gstart + 128;                     // N
    int* col_src = row_ptr + N;                      // E + 3N + 64 (padded rows)
    int* pos     = col_src + E + 3 * N + 64;         // E

    size_t zbytes = (size_t)((char*)zend - (char*)zstart);
    hipMemsetAsync(zstart, 0, zbytes, stream);

    int hbBlocks = ((E > N ? E : N) + 255) / 256;
    hipLaunchKernelGGL(wcvt_hb_kernel, dim3(24 + hbBlocks), dim3(256), 0, stream,
                       Wsrc, Wdst, attn, Wt16, att16, dstp, deg, pos, gidp, gstart, N, E);
    hipLaunchKernelGGL(rowptr_kernel, dim3(nb), dim3(256), 0, stream,
                       deg, row_ptr, gbase, gstart, cntg, N);

    int gemmBlocks = (N + 63) / 64;
    int scatBlocks = (E + 511) / 512;
    for (int l = 0; l < 3; l++) {
        const float* hsrcp = (l == 0) ? feat : hmean;
        int sb = (l == 0) ? scatBlocks : 0;   // layer-0 gemm grid also scatters
        int pb = (l >= 1) ? NG : 0;           // layer>=1 gemm grid also runs pooled(l-1)
        hipLaunchKernelGGL(gemm_kernel, dim3(gemmBlocks + sb + pb), dim3(512), 0, stream,
                           hsrcp, bnsum + (l - 1) * 64, bnsq + (l - 1) * 64,
                           bn_g + (l - 1) * 64, bn_b + (l - 1) * 64,
                           (l == 0) ? 1 : 0, 1.f / (float)N,
                           Wt16 + (size_t)l * 32768, bsrc + l * 256, bdst + l * 256,
                           fsh, fdh, N, gemmBlocks, sb,
                           srcp, dstp, row_ptr, pos, col_src, E,
                           S + (l - 1) * 8192, cntg,
                           lpW + (size_t)(l - 1) * 4096, lpb + (l - 1) * 64,
                           q + (l - 1) * 8192, qsum + (l - 1) * 64, qsq + (l - 1) * 64);
        hipLaunchKernelGGL(gat_kernel, dim3((N + 3) / 4), dim3(256), 0, stream,
                           fsh, fdh, att16 + l * 256, row_ptr, deg, col_src, hmean, N);
        hipLaunchKernelGGL(stats_kernel, dim3(128), dim3(256), 0, stream,
                           hmean, gidp, bnsum + l * 64, bnsq + l * 64, S + l * 8192, N);
    }
    hipLaunchKernelGGL(pooled_a_kernel, dim3(NG), dim3(256), 0, stream,
                       bnsum + 2 * 64, bnsq + 2 * 64, S + 2 * 8192, cntg,
                       bn_g + 2 * 64, bn_b + 2 * 64,
                       lpW + (size_t)2 * 4096, lpb + 2 * 64,
                       q + 2 * 8192, qsum + 2 * 64, qsq + 2 * 64, N);
    hipLaunchKernelGGL(head_kernel, dim3(NG), dim3(256), 0, stream,
                       q, qsum, qsq, lpg, lpbt, blW, blb, blg, blbt,
                       llW, llb, llg, llbt, hh, hsum, hsq, done, out);
}